// Round 2
// baseline (3783.142 us; speedup 1.0000x reference)
//
#include <hip/hip_runtime.h>
#include <cfloat>

#define B_SZ 16
#define CD   256
#define NP   4096
#define KC   1024
#define MT   64      // points per block
#define NT   128     // codes per tile
#define CC   16      // c-depth per chunk
#define TPB  256

// np pairwise_sum replication for n=256: split 128+128, each half 8 accumulators,
// combine ((r0+r1)+(r2+r3))+((r4+r5)+(r6+r7)). __f*_rn forbids contraction.

__global__ void vq_esq(const float* __restrict__ w, float* __restrict__ esq_g)
{
    int k = blockIdx.x * blockDim.x + threadIdx.x;
    if (k >= KC) return;
    const float* wr = w + (size_t)k * CD;
    float halves[2];
    #pragma unroll
    for (int h = 0; h < 2; ++h) {
        const float* a = wr + h * 128;
        float r0 = __fmul_rn(a[0], a[0]);
        float r1 = __fmul_rn(a[1], a[1]);
        float r2 = __fmul_rn(a[2], a[2]);
        float r3 = __fmul_rn(a[3], a[3]);
        float r4 = __fmul_rn(a[4], a[4]);
        float r5 = __fmul_rn(a[5], a[5]);
        float r6 = __fmul_rn(a[6], a[6]);
        float r7 = __fmul_rn(a[7], a[7]);
        for (int i = 8; i < 128; i += 8) {
            r0 = __fadd_rn(r0, __fmul_rn(a[i + 0], a[i + 0]));
            r1 = __fadd_rn(r1, __fmul_rn(a[i + 1], a[i + 1]));
            r2 = __fadd_rn(r2, __fmul_rn(a[i + 2], a[i + 2]));
            r3 = __fadd_rn(r3, __fmul_rn(a[i + 3], a[i + 3]));
            r4 = __fadd_rn(r4, __fmul_rn(a[i + 4], a[i + 4]));
            r5 = __fadd_rn(r5, __fmul_rn(a[i + 5], a[i + 5]));
            r6 = __fadd_rn(r6, __fmul_rn(a[i + 6], a[i + 6]));
            r7 = __fadd_rn(r7, __fmul_rn(a[i + 7], a[i + 7]));
        }
        halves[h] = __fadd_rn(__fadd_rn(__fadd_rn(r0, r1), __fadd_rn(r2, r3)),
                              __fadd_rn(__fadd_rn(r4, r5), __fadd_rn(r6, r7)));
    }
    esq_g[k] = __fadd_rn(halves[0], halves[1]);
}

__global__ void __launch_bounds__(TPB, 2)
vq_fused(const float* __restrict__ x, const float* __restrict__ w,
         const float* __restrict__ esq_g, float* __restrict__ out)
{
    __shared__ float xs[CD][MT];        // 64 KB, c-major: xs[c][p]
    __shared__ float ws[2][CC][NT];     // 16 KB double-buffered, transposed: ws[buf][c][j]
    // total 80 KB exactly -> 2 blocks/CU. xsq / reduction / codes all reuse ws.

    const int tid = threadIdx.x;
    const int blk = blockIdx.x;
    const int b   = blk >> 6;
    const int p0  = (blk & 63) << 6;
    const float* xb = x + (size_t)b * CD * NP;

    // ---- stage xs[c][p] (coalesced float4) ----
    #pragma unroll
    for (int r = 0; r < 16; ++r) {
        int f  = tid + r * TPB;
        int c  = f >> 4;
        int pq = (f & 15) << 2;
        float4 v = *(const float4*)(xb + (size_t)c * NP + p0 + pq);
        *(float4*)&xs[c][pq] = v;
    }
    __syncthreads();

    // ---- x_sq per point, np-pairwise order, staged through ws[0] then to regs ----
    float* xsq_tmp = &ws[0][0][0];
    if (tid < MT) {
        float halves[2];
        #pragma unroll
        for (int h = 0; h < 2; ++h) {
            int cb = h * 128;
            float r0 = __fmul_rn(xs[cb + 0][tid], xs[cb + 0][tid]);
            float r1 = __fmul_rn(xs[cb + 1][tid], xs[cb + 1][tid]);
            float r2 = __fmul_rn(xs[cb + 2][tid], xs[cb + 2][tid]);
            float r3 = __fmul_rn(xs[cb + 3][tid], xs[cb + 3][tid]);
            float r4 = __fmul_rn(xs[cb + 4][tid], xs[cb + 4][tid]);
            float r5 = __fmul_rn(xs[cb + 5][tid], xs[cb + 5][tid]);
            float r6 = __fmul_rn(xs[cb + 6][tid], xs[cb + 6][tid]);
            float r7 = __fmul_rn(xs[cb + 7][tid], xs[cb + 7][tid]);
            for (int i = 8; i < 128; i += 8) {
                r0 = __fadd_rn(r0, __fmul_rn(xs[cb + i + 0][tid], xs[cb + i + 0][tid]));
                r1 = __fadd_rn(r1, __fmul_rn(xs[cb + i + 1][tid], xs[cb + i + 1][tid]));
                r2 = __fadd_rn(r2, __fmul_rn(xs[cb + i + 2][tid], xs[cb + i + 2][tid]));
                r3 = __fadd_rn(r3, __fmul_rn(xs[cb + i + 3][tid], xs[cb + i + 3][tid]));
                r4 = __fadd_rn(r4, __fmul_rn(xs[cb + i + 4][tid], xs[cb + i + 4][tid]));
                r5 = __fadd_rn(r5, __fmul_rn(xs[cb + i + 5][tid], xs[cb + i + 5][tid]));
                r6 = __fadd_rn(r6, __fmul_rn(xs[cb + i + 6][tid], xs[cb + i + 6][tid]));
                r7 = __fadd_rn(r7, __fmul_rn(xs[cb + i + 7][tid], xs[cb + i + 7][tid]));
            }
            halves[h] = __fadd_rn(__fadd_rn(__fadd_rn(r0, r1), __fadd_rn(r2, r3)),
                                  __fadd_rn(__fadd_rn(r4, r5), __fadd_rn(r6, r7)));
        }
        xsq_tmp[tid] = __fadd_rn(halves[0], halves[1]);
    }
    __syncthreads();

    const int pl = (tid & 15) << 2;     // 4 consecutive local points
    const int jl = (tid >> 4) << 3;     // 8 consecutive local codes within tile
    float xq[4] = { xsq_tmp[pl], xsq_tmp[pl + 1], xsq_tmp[pl + 2], xsq_tmp[pl + 3] };
    __syncthreads();                    // xq reads done before first ws write

    // ---- staging lane mapping: j = tid>>1 (row), 8 c's per lane ----
    const int sj = tid >> 1;            // 0..127
    const int sc = (tid & 1) << 3;      // 0 or 8

    // prologue: stage chunk 0 (tile 0, c0 = 0) into buf 0
    {
        const float* wr = w + (size_t)sj * CD + sc;
        float4 a = *(const float4*)(wr);
        float4 bq = *(const float4*)(wr + 4);
        ws[0][sc + 0][sj] = a.x;  ws[0][sc + 1][sj] = a.y;
        ws[0][sc + 2][sj] = a.z;  ws[0][sc + 3][sj] = a.w;
        ws[0][sc + 4][sj] = bq.x; ws[0][sc + 5][sj] = bq.y;
        ws[0][sc + 6][sj] = bq.z; ws[0][sc + 7][sj] = bq.w;
    }
    __syncthreads();

    float bestd[4] = {FLT_MAX, FLT_MAX, FLT_MAX, FLT_MAX};
    int   besti[4] = {0, 0, 0, 0};

    for (int tile = 0; tile < KC / NT; ++tile) {        // 8 tiles
        const int n0 = tile * NT;
        // e_sq for this thread's 8 codes (L1-broadcast loads, hidden under compute)
        float4 e0 = *(const float4*)(esq_g + n0 + jl);
        float4 e1 = *(const float4*)(esq_g + n0 + jl + 4);
        float e_[8] = {e0.x, e0.y, e0.z, e0.w, e1.x, e1.y, e1.z, e1.w};

        float acc[4][8];
        #pragma unroll
        for (int i = 0; i < 4; ++i)
            #pragma unroll
            for (int j = 0; j < 8; ++j) acc[i][j] = 0.f;

        #pragma unroll 2
        for (int ch = 0; ch < 16; ++ch) {               // 16 chunks of CC=16 c's
            const int t   = tile * 16 + ch;
            const int cur = t & 1;
            const bool pf = (t + 1) < 128;

            // (a) issue prefetch loads for chunk t+1 EARLY
            float4 pa, pb;
            if (pf) {
                const int tn  = t + 1;
                const int nn0 = (tn >> 4) * NT;
                const int nc0 = (tn & 15) * CC;
                const float* wr = w + (size_t)(nn0 + sj) * CD + nc0 + sc;
                pa = *(const float4*)(wr);
                pb = *(const float4*)(wr + 4);
            }

            // (b) compute chunk t from ws[cur]  (c ascending -> exact np order)
            const int c0 = ch * CC;
            #pragma unroll
            for (int c = 0; c < CC; ++c) {
                float4 xv  = *(const float4*)&xs[c0 + c][pl];
                float4 wv0 = *(const float4*)&ws[cur][c][jl];
                float4 wv1 = *(const float4*)&ws[cur][c][jl + 4];
                const float xr[4] = {xv.x, xv.y, xv.z, xv.w};
                const float wr8[8] = {wv0.x, wv0.y, wv0.z, wv0.w,
                                      wv1.x, wv1.y, wv1.z, wv1.w};
                #pragma unroll
                for (int i = 0; i < 4; ++i)
                    #pragma unroll
                    for (int j = 0; j < 8; ++j)
                        acc[i][j] = fmaf(xr[i], wr8[j], acc[i][j]);
            }

            // (c) write prefetched chunk into the other buffer
            if (pf) {
                const int nb = (t + 1) & 1;
                ws[nb][sc + 0][sj] = pa.x;  ws[nb][sc + 1][sj] = pa.y;
                ws[nb][sc + 2][sj] = pa.z;  ws[nb][sc + 3][sj] = pa.w;
                ws[nb][sc + 4][sj] = pb.x;  ws[nb][sc + 5][sj] = pb.y;
                ws[nb][sc + 6][sj] = pb.z;  ws[nb][sc + 7][sj] = pb.w;
            }
            __syncthreads();
        }

        // d2 = fl(fl(x_sq - fl(2*cross)) + e_sq) — exact np op order
        #pragma unroll
        for (int i = 0; i < 4; ++i) {
            float xqv = xq[i];
            #pragma unroll
            for (int j = 0; j < 8; ++j) {
                int   idx = n0 + jl + j;
                float d2  = __fadd_rn(__fsub_rn(xqv, __fmul_rn(2.0f, acc[i][j])), e_[j]);
                if (d2 < bestd[i]) { bestd[i] = d2; besti[i] = idx; }  // ascending idx
            }
        }
    }

    // ---- cross-thread argmin reduction (lexicographic (d2, idx)), reuse ws ----
    __syncthreads();
    float* redd  = &ws[0][0][0];            // 1024 floats
    int*   redi  = (int*)(redd + 1024);     // 1024 ints (still inside ws[0])
    int*   codes = (int*)&ws[1][0][0];
    {
        int g = tid >> 4;                   // 16 code-groups per point
        #pragma unroll
        for (int i = 0; i < 4; ++i) {
            redd[(pl + i) * 16 + g] = bestd[i];
            redi[(pl + i) * 16 + g] = besti[i];
        }
    }
    __syncthreads();
    if (tid < MT) {
        float bd = FLT_MAX; int bi = 0x7fffffff;
        #pragma unroll
        for (int g = 0; g < 16; ++g) {
            float d = redd[tid * 16 + g];
            int   i = redi[tid * 16 + g];
            if (d < bd || (d == bd && i < bi)) { bd = d; bi = i; }
        }
        codes[tid] = bi;
        out[(size_t)b * NP + p0 + tid] = (float)bi;
    }
    __syncthreads();

    // ---- gather x_new[b][c][p] = weight[code[p]][c] (coalesced stores) ----
    {
        float* outx = out + (size_t)B_SZ * NP;
        int p  = tid & 63;
        int cg = tid >> 6;
        const float* wr = w + (size_t)codes[p] * CD;
        size_t obase = (size_t)b * CD * NP + (size_t)p0 + p;
        #pragma unroll 4
        for (int r = 0; r < 64; ++r) {
            int c = (cg << 6) + r;
            outx[obase + (size_t)c * NP] = wr[c];
        }
    }
}

extern "C" void kernel_launch(void* const* d_in, const int* in_sizes, int n_in,
                              void* d_out, int out_size, void* d_ws, size_t ws_size,
                              hipStream_t stream)
{
    const float* x = (const float*)d_in[0];     // [16,256,64,64]
    const float* w = (const float*)d_in[1];     // [1024,256]
    float* out    = (float*)d_out;              // 65536 code + 16777216 x_new
    float* esq_g  = (float*)d_ws;               // 4 KB scratch

    hipLaunchKernelGGL(vq_esq,   dim3(4),    dim3(TPB), 0, stream, w, esq_g);
    hipLaunchKernelGGL(vq_fused, dim3(1024), dim3(TPB), 0, stream, x, w, esq_g, out);
}

// Round 3
// 524.332 us; speedup vs baseline: 7.2152x; 7.2152x over previous
//
#include <hip/hip_runtime.h>
#include <cfloat>

#define B_SZ 16
#define CD   256
#define NP   4096
#define KC   1024
#define MT   64      // points per block
#define NT   128     // codes per tile
#define CC   16      // c-depth per chunk
#define TPB  256

// np pairwise_sum replication for n=256: split 128+128, each half 8 accumulators,
// combine ((r0+r1)+(r2+r3))+((r4+r5)+(r6+r7)). __f*_rn forbids contraction.

__global__ void vq_esq(const float* __restrict__ w, float* __restrict__ esq_g)
{
    int k = blockIdx.x * blockDim.x + threadIdx.x;
    if (k >= KC) return;
    const float* wr = w + (size_t)k * CD;
    float halves[2];
    #pragma unroll
    for (int h = 0; h < 2; ++h) {
        const float* a = wr + h * 128;
        float r0 = __fmul_rn(a[0], a[0]);
        float r1 = __fmul_rn(a[1], a[1]);
        float r2 = __fmul_rn(a[2], a[2]);
        float r3 = __fmul_rn(a[3], a[3]);
        float r4 = __fmul_rn(a[4], a[4]);
        float r5 = __fmul_rn(a[5], a[5]);
        float r6 = __fmul_rn(a[6], a[6]);
        float r7 = __fmul_rn(a[7], a[7]);
        for (int i = 8; i < 128; i += 8) {
            r0 = __fadd_rn(r0, __fmul_rn(a[i + 0], a[i + 0]));
            r1 = __fadd_rn(r1, __fmul_rn(a[i + 1], a[i + 1]));
            r2 = __fadd_rn(r2, __fmul_rn(a[i + 2], a[i + 2]));
            r3 = __fadd_rn(r3, __fmul_rn(a[i + 3], a[i + 3]));
            r4 = __fadd_rn(r4, __fmul_rn(a[i + 4], a[i + 4]));
            r5 = __fadd_rn(r5, __fmul_rn(a[i + 5], a[i + 5]));
            r6 = __fadd_rn(r6, __fmul_rn(a[i + 6], a[i + 6]));
            r7 = __fadd_rn(r7, __fmul_rn(a[i + 7], a[i + 7]));
        }
        halves[h] = __fadd_rn(__fadd_rn(__fadd_rn(r0, r1), __fadd_rn(r2, r3)),
                              __fadd_rn(__fadd_rn(r4, r5), __fadd_rn(r6, r7)));
    }
    esq_g[k] = __fadd_rn(halves[0], halves[1]);
}

// 8 FMA for one point-row i against the 8 staged codes (all indices literal)
#define FMA_ROW(i, xc)                              \
    acc##i##0 = fmaf((xc), wv0.x, acc##i##0);       \
    acc##i##1 = fmaf((xc), wv0.y, acc##i##1);       \
    acc##i##2 = fmaf((xc), wv0.z, acc##i##2);       \
    acc##i##3 = fmaf((xc), wv0.w, acc##i##3);       \
    acc##i##4 = fmaf((xc), wv1.x, acc##i##4);       \
    acc##i##5 = fmaf((xc), wv1.y, acc##i##5);       \
    acc##i##6 = fmaf((xc), wv1.z, acc##i##6);       \
    acc##i##7 = fmaf((xc), wv1.w, acc##i##7);

// d2 = fl(fl(x_sq - fl(2*cross)) + e_sq), exact np order; ascending j keeps first-min
#define D2_ONE(i, j, ev)                                                          \
    {                                                                             \
        float d2 = __fadd_rn(__fsub_rn(xq[i], __fmul_rn(2.0f, acc##i##j)), (ev)); \
        if (d2 < bestd[i]) { bestd[i] = d2; besti[i] = n0 + jl + j; }             \
    }

#define D2_ROW(i)                                                                 \
    D2_ONE(i, 0, e0.x) D2_ONE(i, 1, e0.y) D2_ONE(i, 2, e0.z) D2_ONE(i, 3, e0.w)  \
    D2_ONE(i, 4, e1.x) D2_ONE(i, 5, e1.y) D2_ONE(i, 6, e1.z) D2_ONE(i, 7, e1.w)

#define DECL_ACC(i) \
    float acc##i##0 = 0.f, acc##i##1 = 0.f, acc##i##2 = 0.f, acc##i##3 = 0.f, \
          acc##i##4 = 0.f, acc##i##5 = 0.f, acc##i##6 = 0.f, acc##i##7 = 0.f;

__global__ void __launch_bounds__(TPB, 2)
vq_fused(const float* __restrict__ x, const float* __restrict__ w,
         const float* __restrict__ esq_g, float* __restrict__ out)
{
    __shared__ float xs[CD][MT];        // 64 KB, c-major: xs[c][p]
    __shared__ float ws[2][CC][NT];     // 16 KB double-buffered, transposed: ws[buf][c][j]
    // exactly 80 KB -> 2 blocks/CU. xsq / reduction / codes reuse ws.

    const int tid = threadIdx.x;
    const int blk = blockIdx.x;
    const int b   = blk >> 6;
    const int p0  = (blk & 63) << 6;
    const float* xb = x + (size_t)b * CD * NP;

    // ---- stage xs[c][p] (coalesced float4) ----
    #pragma unroll
    for (int r = 0; r < 16; ++r) {
        int f  = tid + r * TPB;
        int c  = f >> 4;
        int pq = (f & 15) << 2;
        float4 v = *(const float4*)(xb + (size_t)c * NP + p0 + pq);
        *(float4*)&xs[c][pq] = v;
    }
    __syncthreads();                                    // A: xs staged

    // staging lane mapping: 2 float4 loads, j varies fastest across lanes
    const int sj = tid & 63;                            // row (code) 0..63 (+64 on r=1)
    const int sc = (tid >> 6) << 2;                     // c-slot 0,4,8,12
    const float* wbase = w + (size_t)sj * CD + sc;      // + n0*CD + nc0 per chunk

    // ---- x_sq (tid<64) into ws[1] scratch, concurrently stage chunk 0 -> ws[0] ----
    float* xsq_tmp = &ws[1][0][0];
    if (tid < MT) {
        float halves[2];
        #pragma unroll
        for (int h = 0; h < 2; ++h) {
            int cb = h * 128;
            float r0 = __fmul_rn(xs[cb + 0][tid], xs[cb + 0][tid]);
            float r1 = __fmul_rn(xs[cb + 1][tid], xs[cb + 1][tid]);
            float r2 = __fmul_rn(xs[cb + 2][tid], xs[cb + 2][tid]);
            float r3 = __fmul_rn(xs[cb + 3][tid], xs[cb + 3][tid]);
            float r4 = __fmul_rn(xs[cb + 4][tid], xs[cb + 4][tid]);
            float r5 = __fmul_rn(xs[cb + 5][tid], xs[cb + 5][tid]);
            float r6 = __fmul_rn(xs[cb + 6][tid], xs[cb + 6][tid]);
            float r7 = __fmul_rn(xs[cb + 7][tid], xs[cb + 7][tid]);
            for (int i = 8; i < 128; i += 8) {
                r0 = __fadd_rn(r0, __fmul_rn(xs[cb + i + 0][tid], xs[cb + i + 0][tid]));
                r1 = __fadd_rn(r1, __fmul_rn(xs[cb + i + 1][tid], xs[cb + i + 1][tid]));
                r2 = __fadd_rn(r2, __fmul_rn(xs[cb + i + 2][tid], xs[cb + i + 2][tid]));
                r3 = __fadd_rn(r3, __fmul_rn(xs[cb + i + 3][tid], xs[cb + i + 3][tid]));
                r4 = __fadd_rn(r4, __fmul_rn(xs[cb + i + 4][tid], xs[cb + i + 4][tid]));
                r5 = __fadd_rn(r5, __fmul_rn(xs[cb + i + 5][tid], xs[cb + i + 5][tid]));
                r6 = __fadd_rn(r6, __fmul_rn(xs[cb + i + 6][tid], xs[cb + i + 6][tid]));
                r7 = __fadd_rn(r7, __fmul_rn(xs[cb + i + 7][tid], xs[cb + i + 7][tid]));
            }
            halves[h] = __fadd_rn(__fadd_rn(__fadd_rn(r0, r1), __fadd_rn(r2, r3)),
                                  __fadd_rn(__fadd_rn(r4, r5), __fadd_rn(r6, r7)));
        }
        xsq_tmp[tid] = __fadd_rn(halves[0], halves[1]);
    }
    {   // stage chunk 0 (n0=0, nc0=0) into ws[0]
        #pragma unroll
        for (int r = 0; r < 2; ++r) {
            int j = sj + (r << 6);
            float4 v = *(const float4*)(w + (size_t)j * CD + sc);
            ws[0][sc + 0][j] = v.x; ws[0][sc + 1][j] = v.y;
            ws[0][sc + 2][j] = v.z; ws[0][sc + 3][j] = v.w;
        }
    }
    __syncthreads();                                    // B: xsq + chunk0 ready

    const int pl = (tid & 15) << 2;     // 4 consecutive local points
    const int jl = (tid >> 4) << 3;     // 8 consecutive local codes within tile
    float xq[4] = { xsq_tmp[pl], xsq_tmp[pl + 1], xsq_tmp[pl + 2], xsq_tmp[pl + 3] };
    __syncthreads();                                    // C: xq read before ws[1] write

    float bestd[4] = {FLT_MAX, FLT_MAX, FLT_MAX, FLT_MAX};
    int   besti[4] = {0, 0, 0, 0};

    for (int tile = 0; tile < KC / NT; ++tile) {        // 8 tiles of 128 codes
        const int n0 = tile * NT;
        // e_sq for this thread's 8 codes (L1-broadcast, hidden under compute)
        float4 e0 = *(const float4*)(esq_g + n0 + jl);
        float4 e1 = *(const float4*)(esq_g + n0 + jl + 4);

        DECL_ACC(0) DECL_ACC(1) DECL_ACC(2) DECL_ACC(3)

        for (int ch = 0; ch < CD / CC; ++ch) {          // 16 chunks of 16 c's
            const int t   = tile * (CD / CC) + ch;
            const int cur = t & 1;

            // (a) issue prefetch loads for chunk t+1 (masked wrap: last is dummy)
            const int tn  = (t + 1) & 127;
            const size_t poff = (size_t)((tn >> 4) << 7) * CD + ((tn & 15) << 4);
            float4 pa = *(const float4*)(wbase + poff);
            float4 pb = *(const float4*)(wbase + poff + (size_t)64 * CD);

            // (b) compute chunk t from ws[cur] (c ascending -> exact np fma order)
            const int c0 = ch * CC;
            #pragma unroll
            for (int c = 0; c < CC; ++c) {
                float4 xv  = *(const float4*)&xs[c0 + c][pl];
                float4 wv0 = *(const float4*)&ws[cur][c][jl];
                float4 wv1 = *(const float4*)&ws[cur][c][jl + 4];
                FMA_ROW(0, xv.x)
                FMA_ROW(1, xv.y)
                FMA_ROW(2, xv.z)
                FMA_ROW(3, xv.w)
            }

            // (c) write prefetched chunk into the other buffer
            {
                const int nb = cur ^ 1;
                ws[nb][sc + 0][sj]      = pa.x; ws[nb][sc + 1][sj]      = pa.y;
                ws[nb][sc + 2][sj]      = pa.z; ws[nb][sc + 3][sj]      = pa.w;
                ws[nb][sc + 0][sj + 64] = pb.x; ws[nb][sc + 1][sj + 64] = pb.y;
                ws[nb][sc + 2][sj + 64] = pb.z; ws[nb][sc + 3][sj + 64] = pb.w;
            }
            __syncthreads();                            // one barrier per chunk
        }

        D2_ROW(0) D2_ROW(1) D2_ROW(2) D2_ROW(3)
    }

    // ---- cross-thread argmin reduction (lexicographic (d2, idx)), reuse ws ----
    __syncthreads();
    float* redd  = &ws[0][0][0];            // 1024 floats
    int*   redi  = (int*)(redd + 1024);     // 1024 ints (rest of ws[0])
    int*   codes = (int*)&ws[1][0][0];
    {
        int g = tid >> 4;                   // 16 code-groups per point
        #pragma unroll
        for (int i = 0; i < 4; ++i) {
            redd[(pl + i) * 16 + g] = bestd[i];
            redi[(pl + i) * 16 + g] = besti[i];
        }
    }
    __syncthreads();
    if (tid < MT) {
        float bd = FLT_MAX; int bi = 0x7fffffff;
        #pragma unroll
        for (int g = 0; g < 16; ++g) {
            float d = redd[tid * 16 + g];
            int   i = redi[tid * 16 + g];
            if (d < bd || (d == bd && i < bi)) { bd = d; bi = i; }
        }
        codes[tid] = bi;
        out[(size_t)b * NP + p0 + tid] = (float)bi;
    }
    __syncthreads();

    // ---- gather x_new[b][c][p] = weight[code[p]][c] (coalesced stores) ----
    {
        float* outx = out + (size_t)B_SZ * NP;
        int p  = tid & 63;
        int cg = tid >> 6;
        const float* wr = w + (size_t)codes[p] * CD;
        size_t obase = (size_t)b * CD * NP + (size_t)p0 + p;
        #pragma unroll 4
        for (int r = 0; r < 64; ++r) {
            int c = (cg << 6) + r;
            outx[obase + (size_t)c * NP] = wr[c];
        }
    }
}

extern "C" void kernel_launch(void* const* d_in, const int* in_sizes, int n_in,
                              void* d_out, int out_size, void* d_ws, size_t ws_size,
                              hipStream_t stream)
{
    const float* x = (const float*)d_in[0];     // [16,256,64,64]
    const float* w = (const float*)d_in[1];     // [1024,256]
    float* out    = (float*)d_out;              // 65536 code + 16777216 x_new
    float* esq_g  = (float*)d_ws;               // 4 KB scratch

    hipLaunchKernelGGL(vq_esq,   dim3(4),    dim3(TPB), 0, stream, w, esq_g);
    hipLaunchKernelGGL(vq_fused, dim3(1024), dim3(TPB), 0, stream, x, w, esq_g, out);
}